// Round 1
// baseline (261.804 us; speedup 1.0000x reference)
//
#include <hip/hip_runtime.h>

// ---- problem constants ----
#define Bq   4
#define Sq   2048
#define Eq   1024
#define Hq   16
#define HDq  64
#define Mq   (Bq*Sq)       // 8192
#define N1q  (3*Eq)        // 3072
#define Kq   Eq            // 1024

#define NX4  (Mq*Kq/4)     // x float4 count        2097152
#define NW4  (N1q*Kq/4)    // w_qkv float4 count     786432
#define NP4  (Eq*Kq/4)     // w_proj float4 count    262144

typedef __bf16 bf16x8 __attribute__((ext_vector_type(8)));
typedef __bf16 bf16x4 __attribute__((ext_vector_type(4)));
typedef float  f32x4  __attribute__((ext_vector_type(4)));
typedef float  f32x16 __attribute__((ext_vector_type(16)));

#define GAS __attribute__((address_space(1)))
#define LAS __attribute__((address_space(3)))

__device__ __forceinline__ void gl2lds16(const void* g, void* l) {
  __builtin_amdgcn_global_load_lds((GAS const void*)g, (LAS void*)l, 16, 0, 0);
}

__device__ __forceinline__ unsigned pack2(float a, float b) {
  union { __bf16 h[2]; unsigned u; } x;
  x.h[0] = (__bf16)a; x.h[1] = (__bf16)b; return x.u;
}

// raw v_exp_f32 (args here are always <= -6 or -1e30: no denorm-fixup needed)
__device__ __forceinline__ float fexp2(float x) {
#if __has_builtin(__builtin_amdgcn_exp2f)
  return __builtin_amdgcn_exp2f(x);
#else
  return exp2f(x);
#endif
}

// ---- single fused fp32->bf16 convert for all three inputs --------------
// w_qkv Q-rows (row%192 < 64) get HD^-0.5*log2(e) folded in so attention
// scores exit MFMA already in base-2 domain.
__global__ __launch_bounds__(256) void cvt_all(const float* __restrict__ x,
                                               const float* __restrict__ wqkv,
                                               const float* __restrict__ wproj,
                                               __bf16* __restrict__ xb,
                                               __bf16* __restrict__ wqkvb,
                                               __bf16* __restrict__ wprojb) {
  int i = blockIdx.x * 256 + threadIdx.x;
  const float* src; __bf16* dst; int j; float sc = 1.0f;
  if (i < NX4) {
    src = x; dst = xb; j = i;
  } else if (i < NX4 + NW4) {
    j = i - NX4; src = wqkv; dst = wqkvb;
    const int row = j >> 8;                    // K=1024 -> 256 float4/row
    if ((row % 192) < 64) sc = 0.18033688011112042f;
  } else {
    j = i - NX4 - NW4; src = wproj; dst = wprojb;
  }
  float4 v = ((const float4*)src)[j];
  bf16x4 o = { (__bf16)(v.x * sc), (__bf16)(v.y * sc),
               (__bf16)(v.z * sc), (__bf16)(v.w * sc) };
  ((bf16x4*)dst)[j] = o;
}

// ---------------- GEMM  C = A(MxK) * B(NxK)^T  (both K-major, bf16) ------
// 128x128-tile 2-phase kernel, kept for the proj GEMM (grid 512 blocks).
// LDS chunk-XOR swizzle: LDS[row][c] = global[row][c ^ ((row>>1)&3)].
template <int MODE>
__global__ __launch_bounds__(256) void gemm_bt(const __bf16* __restrict__ A,
                                               const __bf16* __restrict__ Bw,
                                               int N, int K,
                                               __bf16* __restrict__ cbf,
                                               const float* __restrict__ bias,
                                               float* __restrict__ cf32) {
  __shared__ __align__(16) __bf16 As[128 * 32];
  __shared__ __align__(16) __bf16 Bs[128 * 32];
  const int tid  = threadIdx.x;
  const int wave = tid >> 6, lane = tid & 63;
  const int quad = lane >> 4, l15 = lane & 15;
  const int wm = wave & 1, wn = wave >> 1;
  const int bm0 = blockIdx.x * 128;
  const int bn0 = blockIdx.y * 128;

  f32x4 acc[4][4] = {};

  const int ar = tid >> 2;
  const int ac = ((tid & 3) ^ ((tid >> 3) & 3)) * 8;   // swizzled global chunk
  const __bf16* Ag0 = A  + (long)(bm0 + ar) * K + ac;
  const __bf16* Bg0 = Bw + (long)(bn0 + ar) * K + ac;
  __bf16* As0 = As + wave * 512; __bf16* As1 = As + 2048 + wave * 512;
  __bf16* Bs0 = Bs + wave * 512; __bf16* Bs1 = Bs + 2048 + wave * 512;

  const int fsw = (l15 >> 1) & 3;                      // fragment-read swizzle

  for (int kc = 0; kc < K; kc += 32) {
    gl2lds16(Ag0 + kc,          As0);
    gl2lds16(Ag0 + 64 * K + kc, As1);
    gl2lds16(Bg0 + kc,          Bs0);
    gl2lds16(Bg0 + 64 * K + kc, Bs1);
    __syncthreads();

    bf16x8 af[4], bfr[4];
#pragma unroll
    for (int mt = 0; mt < 4; mt++)
      af[mt] = *(const bf16x8*)&As[(wm * 64 + mt * 16 + l15) * 32 + (quad ^ fsw) * 8];
#pragma unroll
    for (int nt = 0; nt < 4; nt++)
      bfr[nt] = *(const bf16x8*)&Bs[(wn * 64 + nt * 16 + l15) * 32 + (quad ^ fsw) * 8];
#pragma unroll
    for (int mt = 0; mt < 4; mt++)
#pragma unroll
      for (int nt = 0; nt < 4; nt++)
        acc[mt][nt] = __builtin_amdgcn_mfma_f32_16x16x32_bf16(af[mt], bfr[nt], acc[mt][nt], 0, 0, 0);
    __syncthreads();
  }

#pragma unroll
  for (int nt = 0; nt < 4; nt++) {
    const int n = bn0 + wn * 64 + nt * 16 + l15;
    float bv = 0.f;
    if (MODE == 1) bv = bias[n];
#pragma unroll
    for (int mt = 0; mt < 4; mt++) {
      const int mbase = bm0 + wm * 64 + mt * 16 + quad * 4;
#pragma unroll
      for (int r = 0; r < 4; r++) {
        const long m = mbase + r;
        if (MODE == 0) cbf[m * N + n] = (__bf16)acc[mt][nt][r];
        else           cf32[m * N + n] = acc[mt][nt][r] + bv;
      }
    }
  }
}

// ---------------- 256x256 8-phase GEMM (QKV):  C = A(MxK)*B(NxK)^T -------
// m201-style schedule in plain HIP. BK=64 split in 2 kk-halves; LDS is
// [buf][kk][256][32] per matrix with the PROVEN chunk-XOR swizzle
// (LDS[row][c] = G[row][c ^ ((row>>1)&3)], 0 bank conflicts measured on
// the 128^2 kernel). Per K-tile: 4 phases of 16 MFMA = (kk, m-half); B
// fragments register-reused across m-halves. Half-tile prefetch stream
// (order per tile: B.kk0, A.kk0, B.kk1, A.kk1; 2 gl_lds each) runs 3
// half-tiles ahead; counted s_waitcnt vmcnt(6) once per K-tile, never 0
// in steady state. Region-lifetime check: each half-tile is issued exactly
// one phase after its last reader's post-MFMA barrier:
//   phase1 reads {A.kk0 mh0, B.kk0}, issues (t+1).A.kk1  (other buffer)
//   phase2 reads {A.kk0 mh1},        issues (t+2).B.kk0  (last read ph1)
//   phase3 reads {A.kk1 mh0, B.kk1}, issues (t+2).A.kk0  (last read ph2)
//   phase4 reads {A.kk1 mh1},        issues (t+2).B.kk1  (last read ph3)
// Requires M%256==0, N%256==0, K%64==0, K>=192.
#define WAITVM(n) asm volatile("s_waitcnt vmcnt(" #n ")" ::: "memory")

#define STG_A(t, kk) do {                                              \
    const __bf16* g_ = ag + (t) * 64 + (kk) * 32;                      \
    __bf16* d_ = As + (((t) & 1) * 2 + (kk)) * 8192 + w * 512;         \
    gl2lds16(g_, d_); gl2lds16(g_ + rowK128, d_ + 4096); } while (0)

#define STG_B(t, kk) do {                                              \
    const __bf16* g_ = bg + (t) * 64 + (kk) * 32;                      \
    __bf16* d_ = Bs + (((t) & 1) * 2 + (kk)) * 8192 + w * 512;         \
    gl2lds16(g_, d_); gl2lds16(g_ + rowK128, d_ + 4096); } while (0)

#define PH_MMA(AF, BF, MOFF)                                           \
  __builtin_amdgcn_s_barrier();                                        \
  asm volatile("s_waitcnt lgkmcnt(0)" ::: "memory");                   \
  __builtin_amdgcn_sched_barrier(0);                                   \
  __builtin_amdgcn_s_setprio(1);                                       \
  _Pragma("unroll")                                                    \
  for (int i_ = 0; i_ < 4; i_++)                                       \
    _Pragma("unroll")                                                  \
    for (int n_ = 0; n_ < 4; n_++)                                     \
      acc[(MOFF) + i_][n_] = __builtin_amdgcn_mfma_f32_16x16x32_bf16(  \
          AF[i_], BF[n_], acc[(MOFF) + i_][n_], 0, 0, 0);              \
  __builtin_amdgcn_s_setprio(0);                                       \
  __builtin_amdgcn_sched_barrier(0);                                   \
  __builtin_amdgcn_s_barrier();

__global__ __launch_bounds__(512, 2) void gemm256(const __bf16* __restrict__ A,
                                                  const __bf16* __restrict__ Bw,
                                                  int N, int K,
                                                  __bf16* __restrict__ C) {
  __shared__ __align__(16) __bf16 As[2 * 2 * 256 * 32];  // 64 KiB
  __shared__ __align__(16) __bf16 Bs[2 * 2 * 256 * 32];  // 64 KiB

  const int tid  = threadIdx.x;
  const int w    = tid >> 6, lane = tid & 63;
  const int quad = lane >> 4, l15 = lane & 15;
  const int wm = w & 1, wn = w >> 1;                 // wave grid 2(M) x 4(N)
  const int fsw = (l15 >> 1) & 3;
  const int bm0 = blockIdx.x * 256, bn0 = blockIdx.y * 256;

  // staging: wave w loads rows w*16..w*16+15 (+128 for 2nd issue), lane ->
  // row w*16+(lane>>2), lds chunk lane&3, global chunk (lane&3)^((lane>>3)&3)
  const int gch8 = ((lane & 3) ^ ((lane >> 3) & 3)) * 8;
  const __bf16* ag = A  + (long)(bm0 + w * 16 + (lane >> 2)) * K + gch8;
  const __bf16* bg = Bw + (long)(bn0 + w * 16 + (lane >> 2)) * K + gch8;
  const long rowK128 = (long)128 * K;

  const int a_rd = (wm * 128 + l15) * 32 + (quad ^ fsw) * 8;
  const int b_rd = (wn * 64  + l15) * 32 + (quad ^ fsw) * 8;

  f32x4 acc[8][4] = {};
  const int NT = K >> 6;

  // prologue: t0.{B0,A0,B1,A1}, t1.{B0,A0,B1}; vmcnt(6) -> tile0 resident
  STG_B(0, 0); STG_A(0, 0); STG_B(0, 1); STG_A(0, 1);
  STG_B(1, 0); STG_A(1, 0); STG_B(1, 1);
  WAITVM(6);
  __builtin_amdgcn_s_barrier();

  for (int t = 0; t < NT; ++t) {
    const int ab = (t & 1) * 16384;                  // buffer base (elems)
    bf16x8 af[4], bf0[4], bf1[4];

    // ---- phase 1: kk0, mh0 ----
#pragma unroll
    for (int i = 0; i < 4; i++) af[i]  = *(const bf16x8*)&As[ab + a_rd + i * 512];
#pragma unroll
    for (int n = 0; n < 4; n++) bf0[n] = *(const bf16x8*)&Bs[ab + b_rd + n * 512];
    if (t + 1 < NT) STG_A(t + 1, 1);
    PH_MMA(af, bf0, 0)

    // ---- phase 2: kk0, mh1 ----
#pragma unroll
    for (int i = 0; i < 4; i++) af[i] = *(const bf16x8*)&As[ab + a_rd + (4 + i) * 512];
    if (t + 2 < NT) STG_B(t + 2, 0);
    PH_MMA(af, bf0, 4)

    // ---- phase 3: kk1, mh0 ----
#pragma unroll
    for (int i = 0; i < 4; i++) af[i]  = *(const bf16x8*)&As[ab + 8192 + a_rd + i * 512];
#pragma unroll
    for (int n = 0; n < 4; n++) bf1[n] = *(const bf16x8*)&Bs[ab + 8192 + b_rd + n * 512];
    if (t + 2 < NT) STG_A(t + 2, 0);
    PH_MMA(af, bf1, 0)

    // ---- phase 4: kk1, mh1 (counted vmcnt; tail drains once) ----
#pragma unroll
    for (int i = 0; i < 4; i++) af[i] = *(const bf16x8*)&As[ab + 8192 + a_rd + (4 + i) * 512];
    if (t + 2 < NT) { STG_B(t + 2, 1); WAITVM(6); }
    else if (t + 1 < NT) { WAITVM(0); }
    PH_MMA(af, bf1, 4)
  }

  // ---- epilogue: C write (same per-element accumulation order as 128^2) --
#pragma unroll
  for (int nt = 0; nt < 4; nt++) {
    const int n = bn0 + wn * 64 + nt * 16 + l15;
#pragma unroll
    for (int mt = 0; mt < 8; mt++) {
      const int mb = bm0 + wm * 128 + mt * 16 + quad * 4;
#pragma unroll
      for (int r = 0; r < 4; r++)
        C[(long)(mb + r) * N + n] = (__bf16)acc[mt][nt][r];
    }
  }
}

// ---------------- V transpose: qkv natural layout -> vt[bh][d][s] --------
__global__ __launch_bounds__(256) void transv(const __bf16* __restrict__ qkv,
                                              __bf16* __restrict__ vt) {
  __shared__ __align__(16) __bf16 T[64 * 64];
  const int tid = threadIdx.x, wave = tid >> 6;
  const int bh = blockIdx.x >> 5, st = blockIdx.x & 31;
  const int b = bh >> 4, h = bh & 15;
  const long gbase = (long)(b * Sq + st * 64 + (tid >> 3)) * N1q + h * 192 + 128 + (tid & 7) * 8;
  gl2lds16(qkv + gbase,                  T + wave * 512);
  gl2lds16(qkv + gbase + (long)32 * N1q, T + 2048 + wave * 512);
  __syncthreads();
  const int d = tid >> 2, s4 = (tid & 3) * 16;
  bf16x8 o0, o1;
#pragma unroll
  for (int j = 0; j < 8; j++) o0[j] = T[(s4 + j) * 64 + d];
#pragma unroll
  for (int j = 0; j < 8; j++) o1[j] = T[(s4 + 8 + j) * 64 + d];
  __bf16* dst = vt + (long)(bh * 64 + d) * Sq + st * 64 + s4;
  *(bf16x8*)dst = o0;
  *(bf16x8*)(dst + 8) = o1;
}

// ---------------- flash attention fwd (causal), transposed-scores --------
// Grid 1024, blockIdx = j*256 + k*64 + bh; qt = 4*j + ((k+j)&3) (Latin
// square: per-CU-slot work uniform). Fixed-max base-2 softmax (scale folded
// into w_qkv cvt). Per-nf fusion keeps one f32x16 of scores live.
// launch_bounds(256,2): do NOT tighten (r4: (256,4) forced 64 VGPR+spills).
__global__ __launch_bounds__(256, 2) void attn_fwd(const __bf16* __restrict__ qkv,
                                                   const __bf16* __restrict__ vt,
                                                   __bf16* __restrict__ aout) {
  __shared__ __align__(16) __bf16 Ks[128 * 64];   // [kcol][d], 16B chunks XOR-swizzled
  __shared__ __align__(16) __bf16 Vs[64 * 128];   // [d][kcol], XOR-swizzled

  const int tid = threadIdx.x;
  const int w = tid >> 6, lane = tid & 63;
  const int c = lane & 31, h = lane >> 5;
  const int bi = blockIdx.x;
  const int bh = bi & 63, kk = (bi >> 6) & 3, jr = bi >> 8;
  const int qt = 4 * jr + ((kk + jr) & 3);
  const int b = bh >> 4, head = bh & 15;

  const int krr = lane >> 3, kj = lane & 7;
  const int vrr = lane >> 4, vj = lane & 15;

  const int q_g = qt * 128 + w * 32 + c;

  bf16x8 qf[4];
  const __bf16* qp = qkv + (long)(b * Sq + q_g) * N1q + head * 192 + h * 8;
#pragma unroll
  for (int kc2 = 0; kc2 < 4; kc2++) qf[kc2] = *(const bf16x8*)(qp + kc2 * 16);

  f32x16 oT[2] = {};
  float l_i = 0.f;
  constexpr float MB = 16.0f;   // fixed softmax max (base-2 domain)

  const int nk = qt + 1;
  for (int kt = 0; kt < nk; kt++) {
#pragma unroll
    for (int i = 0; i < 4; i++) {
      const int row = w * 32 + i * 8 + krr;
      gl2lds16(qkv + (long)(b * Sq + kt * 128 + row) * N1q + head * 192 + 64
                   + (kj ^ (krr & 7)) * 8,
               Ks + (w * 32 + i * 8) * 64);
    }
#pragma unroll
    for (int i = 0; i < 4; i++) {
      const int dr = w * 16 + i * 4 + vrr;
      gl2lds16(vt + (long)(bh * 64 + dr) * Sq + kt * 128 + (vj ^ (dr & 7)) * 8,
               Vs + (w * 16 + i * 4) * 128);
    }
    __syncthreads();

    const bool diag = (kt == qt);
    float s_acc = 0.f;

#pragma unroll
    for (int nf = 0; nf < 4; nf++) {
      f32x16 z = {};
#pragma unroll
      for (int kc2 = 0; kc2 < 4; kc2++) {
        bf16x8 kf = *(const bf16x8*)&Ks[(nf * 32 + c) * 64 + (((kc2 * 2 + h) ^ (c & 7)) * 8)];
        z = __builtin_amdgcn_mfma_f32_32x32x16_bf16(kf, qf[kc2], z, 0, 0, 0);
      }
      if (diag) {
#pragma unroll
        for (int r = 0; r < 16; r++) {
          const int kcol = kt * 128 + nf * 32 + (r & 3) + 8 * (r >> 2) + 4 * h;
          if (kcol > q_g) z[r] = -1e30f;
        }
      }
#pragma unroll
      for (int r = 0; r < 16; r++) {
        float p = fexp2(z[r] - MB);
        z[r] = p; s_acc += p;
      }
#pragma unroll
      for (int sub = 0; sub < 2; sub++) {
        const int kc = nf * 2 + sub, base = 8 * sub;
        const unsigned pa0 = pack2(z[base + 0], z[base + 1]);
        const unsigned pa1 = pack2(z[base + 2], z[base + 3]);
        const unsigned pb0 = pack2(z[base + 4], z[base + 5]);
        const unsigned pb1 = pack2(z[base + 6], z[base + 7]);
        const unsigned send0 = h ? pa0 : pb0;
        const unsigned send1 = h ? pa1 : pb1;
        const unsigned recv0 = __shfl_xor(send0, 32);
        const unsigned recv1 = __shfl_xor(send1, 32);
        union { bf16x8 v; unsigned u[4]; } pf;
        pf.u[0] = h ? recv0 : pa0;
        pf.u[1] = h ? recv1 : pa1;
        pf.u[2] = h ? pb0 : recv0;
        pf.u[3] = h ? pb1 : recv1;
#pragma unroll
        for (int nf2 = 0; nf2 < 2; nf2++) {
          bf16x8 vf = *(const bf16x8*)&Vs[(nf2 * 32 + c) * 128 + (((kc * 2 + h) ^ (c & 7)) * 8)];
          oT[nf2] = __builtin_amdgcn_mfma_f32_32x32x16_bf16(vf, pf.v, oT[nf2], 0, 0, 0);
        }
      }
    }
    l_i += s_acc;
    __syncthreads();
  }

  // ---- epilogue ----
  const float l = l_i + __shfl_xor(l_i, 32);
  const float inv = 1.0f / l;
  const long obase = (long)(b * Sq + q_g) * Eq + head * 64;
#pragma unroll
  for (int nf2 = 0; nf2 < 2; nf2++)
#pragma unroll
    for (int g = 0; g < 4; g++) {
      bf16x4 o;
#pragma unroll
      for (int t = 0; t < 4; t++) o[t] = (__bf16)(oT[nf2][g * 4 + t] * inv);
      *(bf16x4*)(aout + obase + nf2 * 32 + 8 * g + 4 * h) = o;
    }
}

// ---------------- launch ----------------
extern "C" void kernel_launch(void* const* d_in, const int* in_sizes, int n_in,
                              void* d_out, int out_size, void* d_ws, size_t ws_size,
                              hipStream_t stream) {
  const float* x      = (const float*)d_in[0];
  const float* w_qkv  = (const float*)d_in[1];
  const float* w_proj = (const float*)d_in[2];
  const float* b_proj = (const float*)d_in[3];
  float* out = (float*)d_out;

  char* w = (char*)d_ws;
  __bf16* xb     = (__bf16*)w; w += (size_t)Mq * Kq * 2;
  __bf16* wqkvb  = (__bf16*)w; w += (size_t)N1q * Kq * 2;
  __bf16* wprojb = (__bf16*)w; w += (size_t)Eq * Kq * 2;
  __bf16* qkvb   = (__bf16*)w; w += (size_t)Mq * N1q * 2;
  __bf16* vtb    = (__bf16*)w; w += (size_t)Bq * Hq * HDq * Sq * 2;
  __bf16* attnb  = (__bf16*)w;

  cvt_all<<<(NX4 + NW4 + NP4) / 256, 256, 0, stream>>>(x, w_qkv, w_proj, xb, wqkvb, wprojb);

  gemm256<<<dim3(Mq / 256, N1q / 256), 512, 0, stream>>>(xb, wqkvb, N1q, Kq, qkvb);

  transv<<<Bq * Hq * (Sq / 64), 256, 0, stream>>>(qkvb, vtb);

  attn_fwd<<<16 * 64, 256, 0, stream>>>(qkvb, vtb, attnb);

  gemm_bt<1><<<dim3(Mq / 128, Eq / 128), 256, 0, stream>>>(attnb, wprojb, Eq, Kq, nullptr, b_proj, out);
}

// Round 2
// 247.418 us; speedup vs baseline: 1.0581x; 1.0581x over previous
//
#include <hip/hip_runtime.h>

// ---- problem constants ----
#define Bq   4
#define Sq   2048
#define Eq   1024
#define Hq   16
#define HDq  64
#define Mq   (Bq*Sq)       // 8192
#define N1q  (3*Eq)        // 3072
#define Kq   Eq            // 1024

#define NX4  (Mq*Kq/4)     // x float4 count        2097152
#define NW4  (N1q*Kq/4)    // w_qkv float4 count     786432
#define NP4  (Eq*Kq/4)     // w_proj float4 count    262144

typedef __bf16 bf16x8 __attribute__((ext_vector_type(8)));
typedef __bf16 bf16x4 __attribute__((ext_vector_type(4)));
typedef float  f32x4  __attribute__((ext_vector_type(4)));
typedef float  f32x16 __attribute__((ext_vector_type(16)));

#define GAS __attribute__((address_space(1)))
#define LAS __attribute__((address_space(3)))

__device__ __forceinline__ void gl2lds16(const void* g, void* l) {
  __builtin_amdgcn_global_load_lds((GAS const void*)g, (LAS void*)l, 16, 0, 0);
}

__device__ __forceinline__ unsigned pack2(float a, float b) {
  union { __bf16 h[2]; unsigned u; } x;
  x.h[0] = (__bf16)a; x.h[1] = (__bf16)b; return x.u;
}

// raw v_exp_f32 (args here are always <= -6 or -1e30: no denorm-fixup needed)
__device__ __forceinline__ float fexp2(float x) {
#if __has_builtin(__builtin_amdgcn_exp2f)
  return __builtin_amdgcn_exp2f(x);
#else
  return exp2f(x);
#endif
}

// ---- single fused fp32->bf16 convert for all three inputs --------------
// w_qkv Q-rows (row%192 < 64) get HD^-0.5*log2(e) folded in so attention
// scores exit MFMA already in base-2 domain.
__global__ __launch_bounds__(256) void cvt_all(const float* __restrict__ x,
                                               const float* __restrict__ wqkv,
                                               const float* __restrict__ wproj,
                                               __bf16* __restrict__ xb,
                                               __bf16* __restrict__ wqkvb,
                                               __bf16* __restrict__ wprojb) {
  int i = blockIdx.x * 256 + threadIdx.x;
  const float* src; __bf16* dst; int j; float sc = 1.0f;
  if (i < NX4) {
    src = x; dst = xb; j = i;
  } else if (i < NX4 + NW4) {
    j = i - NX4; src = wqkv; dst = wqkvb;
    const int row = j >> 8;                    // K=1024 -> 256 float4/row
    if ((row % 192) < 64) sc = 0.18033688011112042f;
  } else {
    j = i - NX4 - NW4; src = wproj; dst = wprojb;
  }
  float4 v = ((const float4*)src)[j];
  bf16x4 o = { (__bf16)(v.x * sc), (__bf16)(v.y * sc),
               (__bf16)(v.z * sc), (__bf16)(v.w * sc) };
  ((bf16x4*)dst)[j] = o;
}

// ---------------- GEMM  C = A(MxK) * B(NxK)^T  (both K-major, bf16) ------
// 128x128 tile, BK=64 (two 32-wide kk-halves per sync: halves the
// vmcnt(0)+lgkmcnt(0) barrier-drain count vs BK=32 — the m97-structure's
// known ~20% stall). LDS 32 KiB single-buffered (m132: 64 KiB dbuf cut
// occupancy and regressed; stay below that).
// LDS chunk-XOR swizzle: LDS[row][c] = global[row][c ^ ((row>>1)&3)]
// within each 32-col kk-half (proven 0 bank conflicts).
// Accumulation order per C element is kk0 then kk1 (ascending K): bit-
// identical to the BK=32 version.
template <int MODE>
__global__ __launch_bounds__(256) void gemm_bt(const __bf16* __restrict__ A,
                                               const __bf16* __restrict__ Bw,
                                               int N, int K,
                                               __bf16* __restrict__ cbf,
                                               const float* __restrict__ bias,
                                               float* __restrict__ cf32) {
  __shared__ __align__(16) __bf16 As[128 * 64];   // [kk][128][32], 16 KiB
  __shared__ __align__(16) __bf16 Bs[128 * 64];
  const int tid  = threadIdx.x;
  const int wave = tid >> 6, lane = tid & 63;
  const int quad = lane >> 4, l15 = lane & 15;
  const int wm = wave & 1, wn = wave >> 1;
  const int bm0 = blockIdx.x * 128;
  const int bn0 = blockIdx.y * 128;

  f32x4 acc[4][4] = {};

  const int ar = tid >> 2;
  const int ac = ((tid & 3) ^ ((tid >> 3) & 3)) * 8;   // swizzled global chunk
  const __bf16* Ag0 = A  + (long)(bm0 + ar) * K + ac;
  const __bf16* Bg0 = Bw + (long)(bn0 + ar) * K + ac;
  // region bases: +0 rows 0-63 kk0, +2048 rows 64-127 kk0,
  //               +4096 rows 0-63 kk1, +6144 rows 64-127 kk1
  __bf16* As0 = As + wave * 512;
  __bf16* Bs0 = Bs + wave * 512;

  const int fsw = (l15 >> 1) & 3;                      // fragment-read swizzle
  const int a_rd = (wm * 64 + l15) * 32 + (quad ^ fsw) * 8;
  const int b_rd = (wn * 64 + l15) * 32 + (quad ^ fsw) * 8;

  for (int kc = 0; kc < K; kc += 64) {
    gl2lds16(Ag0 + kc,               As0);
    gl2lds16(Ag0 + 64 * K + kc,      As0 + 2048);
    gl2lds16(Ag0 + kc + 32,          As0 + 4096);
    gl2lds16(Ag0 + 64 * K + kc + 32, As0 + 6144);
    gl2lds16(Bg0 + kc,               Bs0);
    gl2lds16(Bg0 + 64 * K + kc,      Bs0 + 2048);
    gl2lds16(Bg0 + kc + 32,          Bs0 + 4096);
    gl2lds16(Bg0 + 64 * K + kc + 32, Bs0 + 6144);
    __syncthreads();

    bf16x8 af[4], bfr[4];
    // ---- kk0 (K 0..31 of this step) ----
#pragma unroll
    for (int mt = 0; mt < 4; mt++)
      af[mt] = *(const bf16x8*)&As[a_rd + mt * 512];
#pragma unroll
    for (int nt = 0; nt < 4; nt++)
      bfr[nt] = *(const bf16x8*)&Bs[b_rd + nt * 512];
#pragma unroll
    for (int mt = 0; mt < 4; mt++)
#pragma unroll
      for (int nt = 0; nt < 4; nt++)
        acc[mt][nt] = __builtin_amdgcn_mfma_f32_16x16x32_bf16(af[mt], bfr[nt], acc[mt][nt], 0, 0, 0);

    // ---- kk1 (K 32..63 of this step) ----
    bf16x8 af1[4], bfr1[4];
#pragma unroll
    for (int mt = 0; mt < 4; mt++)
      af1[mt] = *(const bf16x8*)&As[4096 + a_rd + mt * 512];
#pragma unroll
    for (int nt = 0; nt < 4; nt++)
      bfr1[nt] = *(const bf16x8*)&Bs[4096 + b_rd + nt * 512];
#pragma unroll
    for (int mt = 0; mt < 4; mt++)
#pragma unroll
      for (int nt = 0; nt < 4; nt++)
        acc[mt][nt] = __builtin_amdgcn_mfma_f32_16x16x32_bf16(af1[mt], bfr1[nt], acc[mt][nt], 0, 0, 0);
    __syncthreads();
  }

#pragma unroll
  for (int nt = 0; nt < 4; nt++) {
    const int n = bn0 + wn * 64 + nt * 16 + l15;
    float bv = 0.f;
    if (MODE == 1) bv = bias[n];
#pragma unroll
    for (int mt = 0; mt < 4; mt++) {
      const int mbase = bm0 + wm * 64 + mt * 16 + quad * 4;
#pragma unroll
      for (int r = 0; r < 4; r++) {
        const long m = mbase + r;
        if (MODE == 0) cbf[m * N + n] = (__bf16)acc[mt][nt][r];
        else           cf32[m * N + n] = acc[mt][nt][r] + bv;
      }
    }
  }
}

// ---------------- V transpose: qkv natural layout -> vt[bh][d][s] --------
__global__ __launch_bounds__(256) void transv(const __bf16* __restrict__ qkv,
                                              __bf16* __restrict__ vt) {
  __shared__ __align__(16) __bf16 T[64 * 64];
  const int tid = threadIdx.x, wave = tid >> 6;
  const int bh = blockIdx.x >> 5, st = blockIdx.x & 31;
  const int b = bh >> 4, h = bh & 15;
  const long gbase = (long)(b * Sq + st * 64 + (tid >> 3)) * N1q + h * 192 + 128 + (tid & 7) * 8;
  gl2lds16(qkv + gbase,                  T + wave * 512);
  gl2lds16(qkv + gbase + (long)32 * N1q, T + 2048 + wave * 512);
  __syncthreads();
  const int d = tid >> 2, s4 = (tid & 3) * 16;
  bf16x8 o0, o1;
#pragma unroll
  for (int j = 0; j < 8; j++) o0[j] = T[(s4 + j) * 64 + d];
#pragma unroll
  for (int j = 0; j < 8; j++) o1[j] = T[(s4 + 8 + j) * 64 + d];
  __bf16* dst = vt + (long)(bh * 64 + d) * Sq + st * 64 + s4;
  *(bf16x8*)dst = o0;
  *(bf16x8*)(dst + 8) = o1;
}

// ---------------- flash attention fwd (causal), transposed-scores --------
// Grid 1024, blockIdx = j*256 + k*64 + bh; qt = 4*j + ((k+j)&3) (Latin
// square: per-CU-slot work uniform). Fixed-max base-2 softmax (scale folded
// into w_qkv cvt). Per-nf fusion keeps one f32x16 of scores live.
// launch_bounds(256,2): do NOT tighten (r4: (256,4) forced 64 VGPR+spills).
__global__ __launch_bounds__(256, 2) void attn_fwd(const __bf16* __restrict__ qkv,
                                                   const __bf16* __restrict__ vt,
                                                   __bf16* __restrict__ aout) {
  __shared__ __align__(16) __bf16 Ks[128 * 64];   // [kcol][d], 16B chunks XOR-swizzled
  __shared__ __align__(16) __bf16 Vs[64 * 128];   // [d][kcol], XOR-swizzled

  const int tid = threadIdx.x;
  const int w = tid >> 6, lane = tid & 63;
  const int c = lane & 31, h = lane >> 5;
  const int bi = blockIdx.x;
  const int bh = bi & 63, kk = (bi >> 6) & 3, jr = bi >> 8;
  const int qt = 4 * jr + ((kk + jr) & 3);
  const int b = bh >> 4, head = bh & 15;

  const int krr = lane >> 3, kj = lane & 7;
  const int vrr = lane >> 4, vj = lane & 15;

  const int q_g = qt * 128 + w * 32 + c;

  bf16x8 qf[4];
  const __bf16* qp = qkv + (long)(b * Sq + q_g) * N1q + head * 192 + h * 8;
#pragma unroll
  for (int kc2 = 0; kc2 < 4; kc2++) qf[kc2] = *(const bf16x8*)(qp + kc2 * 16);

  f32x16 oT[2] = {};
  float l_i = 0.f;
  constexpr float MB = 16.0f;   // fixed softmax max (base-2 domain)

  const int nk = qt + 1;
  for (int kt = 0; kt < nk; kt++) {
#pragma unroll
    for (int i = 0; i < 4; i++) {
      const int row = w * 32 + i * 8 + krr;
      gl2lds16(qkv + (long)(b * Sq + kt * 128 + row) * N1q + head * 192 + 64
                   + (kj ^ (krr & 7)) * 8,
               Ks + (w * 32 + i * 8) * 64);
    }
#pragma unroll
    for (int i = 0; i < 4; i++) {
      const int dr = w * 16 + i * 4 + vrr;
      gl2lds16(vt + (long)(bh * 64 + dr) * Sq + kt * 128 + (vj ^ (dr & 7)) * 8,
               Vs + (w * 16 + i * 4) * 128);
    }
    __syncthreads();

    const bool diag = (kt == qt);
    float s_acc = 0.f;

#pragma unroll
    for (int nf = 0; nf < 4; nf++) {
      f32x16 z = {};
#pragma unroll
      for (int kc2 = 0; kc2 < 4; kc2++) {
        bf16x8 kf = *(const bf16x8*)&Ks[(nf * 32 + c) * 64 + (((kc2 * 2 + h) ^ (c & 7)) * 8)];
        z = __builtin_amdgcn_mfma_f32_32x32x16_bf16(kf, qf[kc2], z, 0, 0, 0);
      }
      if (diag) {
#pragma unroll
        for (int r = 0; r < 16; r++) {
          const int kcol = kt * 128 + nf * 32 + (r & 3) + 8 * (r >> 2) + 4 * h;
          if (kcol > q_g) z[r] = -1e30f;
        }
      }
#pragma unroll
      for (int r = 0; r < 16; r++) {
        float p = fexp2(z[r] - MB);
        z[r] = p; s_acc += p;
      }
#pragma unroll
      for (int sub = 0; sub < 2; sub++) {
        const int kc = nf * 2 + sub, base = 8 * sub;
        const unsigned pa0 = pack2(z[base + 0], z[base + 1]);
        const unsigned pa1 = pack2(z[base + 2], z[base + 3]);
        const unsigned pb0 = pack2(z[base + 4], z[base + 5]);
        const unsigned pb1 = pack2(z[base + 6], z[base + 7]);
        const unsigned send0 = h ? pa0 : pb0;
        const unsigned send1 = h ? pa1 : pb1;
        const unsigned recv0 = __shfl_xor(send0, 32);
        const unsigned recv1 = __shfl_xor(send1, 32);
        union { bf16x8 v; unsigned u[4]; } pf;
        pf.u[0] = h ? recv0 : pa0;
        pf.u[1] = h ? recv1 : pa1;
        pf.u[2] = h ? pb0 : recv0;
        pf.u[3] = h ? pb1 : recv1;
#pragma unroll
        for (int nf2 = 0; nf2 < 2; nf2++) {
          bf16x8 vf = *(const bf16x8*)&Vs[(nf2 * 32 + c) * 128 + (((kc * 2 + h) ^ (c & 7)) * 8)];
          oT[nf2] = __builtin_amdgcn_mfma_f32_32x32x16_bf16(vf, pf.v, oT[nf2], 0, 0, 0);
        }
      }
    }
    l_i += s_acc;
    __syncthreads();
  }

  // ---- epilogue ----
  const float l = l_i + __shfl_xor(l_i, 32);
  const float inv = 1.0f / l;
  const long obase = (long)(b * Sq + q_g) * Eq + head * 64;
#pragma unroll
  for (int nf2 = 0; nf2 < 2; nf2++)
#pragma unroll
    for (int g = 0; g < 4; g++) {
      bf16x4 o;
#pragma unroll
      for (int t = 0; t < 4; t++) o[t] = (__bf16)(oT[nf2][g * 4 + t] * inv);
      *(bf16x4*)(aout + obase + nf2 * 32 + 8 * g + 4 * h) = o;
    }
}

// ---------------- launch ----------------
extern "C" void kernel_launch(void* const* d_in, const int* in_sizes, int n_in,
                              void* d_out, int out_size, void* d_ws, size_t ws_size,
                              hipStream_t stream) {
  const float* x      = (const float*)d_in[0];
  const float* w_qkv  = (const float*)d_in[1];
  const float* w_proj = (const float*)d_in[2];
  const float* b_proj = (const float*)d_in[3];
  float* out = (float*)d_out;

  char* w = (char*)d_ws;
  __bf16* xb     = (__bf16*)w; w += (size_t)Mq * Kq * 2;
  __bf16* wqkvb  = (__bf16*)w; w += (size_t)N1q * Kq * 2;
  __bf16* wprojb = (__bf16*)w; w += (size_t)Eq * Kq * 2;
  __bf16* qkvb   = (__bf16*)w; w += (size_t)Mq * N1q * 2;
  __bf16* vtb    = (__bf16*)w; w += (size_t)Bq * Hq * HDq * Sq * 2;
  __bf16* attnb  = (__bf16*)w;

  cvt_all<<<(NX4 + NW4 + NP4) / 256, 256, 0, stream>>>(x, w_qkv, w_proj, xb, wqkvb, wprojb);

  gemm_bt<0><<<dim3(Mq / 128, N1q / 128), 256, 0, stream>>>(xb, wqkvb, N1q, Kq, qkvb, nullptr, nullptr);

  transv<<<Bq * Hq * (Sq / 64), 256, 0, stream>>>(qkvb, vtb);

  attn_fwd<<<16 * 64, 256, 0, stream>>>(qkvb, vtb, attnb);

  gemm_bt<1><<<dim3(Mq / 128, Eq / 128), 256, 0, stream>>>(attnb, wprojb, Eq, Kq, nullptr, b_proj, out);
}

// Round 3
// 243.973 us; speedup vs baseline: 1.0731x; 1.0141x over previous
//
#include <hip/hip_runtime.h>

// ---- problem constants ----
#define Bq   4
#define Sq   2048
#define Eq   1024
#define Hq   16
#define HDq  64
#define Mq   (Bq*Sq)       // 8192
#define N1q  (3*Eq)        // 3072
#define Kq   Eq            // 1024

#define NX4  (Mq*Kq/4)     // x float4 count        2097152
#define NW4  (N1q*Kq/4)    // w_qkv float4 count     786432
#define NP4  (Eq*Kq/4)     // w_proj float4 count    262144

typedef __bf16 bf16x8 __attribute__((ext_vector_type(8)));
typedef __bf16 bf16x4 __attribute__((ext_vector_type(4)));
typedef float  f32x4  __attribute__((ext_vector_type(4)));
typedef float  f32x16 __attribute__((ext_vector_type(16)));

#define GAS __attribute__((address_space(1)))
#define LAS __attribute__((address_space(3)))

__device__ __forceinline__ void gl2lds16(const void* g, void* l) {
  __builtin_amdgcn_global_load_lds((GAS const void*)g, (LAS void*)l, 16, 0, 0);
}

__device__ __forceinline__ unsigned pack2(float a, float b) {
  union { __bf16 h[2]; unsigned u; } x;
  x.h[0] = (__bf16)a; x.h[1] = (__bf16)b; return x.u;
}

// v_permlane32_swap_b32: a' = [a.lo32, b.lo32], b' = [a.hi32, b.hi32]
// (VALU lane-swap; replaces ds_bpermute-based __shfl_xor(.,32) which cost
// 8 LDS-conflict cycles per op — the entire 4.46M SQ_LDS_BANK_CONFLICT
// signature of round 2's attn kernel.)
__device__ __forceinline__ void perm32swap(unsigned& a, unsigned& b) {
  asm("v_permlane32_swap_b32 %0, %1" : "+v"(a), "+v"(b));
}

// raw v_exp_f32 (args here are always <= -6 or -1e30: no denorm-fixup needed)
__device__ __forceinline__ float fexp2(float x) {
#if __has_builtin(__builtin_amdgcn_exp2f)
  return __builtin_amdgcn_exp2f(x);
#else
  return exp2f(x);
#endif
}

// ---- single fused fp32->bf16 convert for all three inputs --------------
// w_qkv Q-rows (row%192 < 64) get HD^-0.5*log2(e) folded in so attention
// scores exit MFMA already in base-2 domain.
__global__ __launch_bounds__(256) void cvt_all(const float* __restrict__ x,
                                               const float* __restrict__ wqkv,
                                               const float* __restrict__ wproj,
                                               __bf16* __restrict__ xb,
                                               __bf16* __restrict__ wqkvb,
                                               __bf16* __restrict__ wprojb) {
  int i = blockIdx.x * 256 + threadIdx.x;
  const float* src; __bf16* dst; int j; float sc = 1.0f;
  if (i < NX4) {
    src = x; dst = xb; j = i;
  } else if (i < NX4 + NW4) {
    j = i - NX4; src = wqkv; dst = wqkvb;
    const int row = j >> 8;                    // K=1024 -> 256 float4/row
    if ((row % 192) < 64) sc = 0.18033688011112042f;
  } else {
    j = i - NX4 - NW4; src = wproj; dst = wprojb;
  }
  float4 v = ((const float4*)src)[j];
  bf16x4 o = { (__bf16)(v.x * sc), (__bf16)(v.y * sc),
               (__bf16)(v.z * sc), (__bf16)(v.w * sc) };
  ((bf16x4*)dst)[j] = o;
}

// ---------------- GEMM  C = A(MxK) * B(NxK)^T  (both K-major, bf16) ------
// 128x128 tile, BK=64 (two 32-wide kk-halves per sync: halves the
// vmcnt(0)+lgkmcnt(0) barrier-drain count vs BK=32 — measured r2:
// 72.5 -> ~65 us per GEMM). LDS 32 KiB single-buffered.
// LDS chunk-XOR swizzle: LDS[row][c] = global[row][c ^ ((row>>1)&3)]
// within each 32-col kk-half (proven 0 bank conflicts).
template <int MODE>
__global__ __launch_bounds__(256) void gemm_bt(const __bf16* __restrict__ A,
                                               const __bf16* __restrict__ Bw,
                                               int N, int K,
                                               __bf16* __restrict__ cbf,
                                               const float* __restrict__ bias,
                                               float* __restrict__ cf32) {
  __shared__ __align__(16) __bf16 As[128 * 64];   // [kk][128][32], 16 KiB
  __shared__ __align__(16) __bf16 Bs[128 * 64];
  const int tid  = threadIdx.x;
  const int wave = tid >> 6, lane = tid & 63;
  const int quad = lane >> 4, l15 = lane & 15;
  const int wm = wave & 1, wn = wave >> 1;
  const int bm0 = blockIdx.x * 128;
  const int bn0 = blockIdx.y * 128;

  f32x4 acc[4][4] = {};

  const int ar = tid >> 2;
  const int ac = ((tid & 3) ^ ((tid >> 3) & 3)) * 8;   // swizzled global chunk
  const __bf16* Ag0 = A  + (long)(bm0 + ar) * K + ac;
  const __bf16* Bg0 = Bw + (long)(bn0 + ar) * K + ac;
  // region bases: +0 rows 0-63 kk0, +2048 rows 64-127 kk0,
  //               +4096 rows 0-63 kk1, +6144 rows 64-127 kk1
  __bf16* As0 = As + wave * 512;
  __bf16* Bs0 = Bs + wave * 512;

  const int fsw = (l15 >> 1) & 3;                      // fragment-read swizzle
  const int a_rd = (wm * 64 + l15) * 32 + (quad ^ fsw) * 8;
  const int b_rd = (wn * 64 + l15) * 32 + (quad ^ fsw) * 8;

  for (int kc = 0; kc < K; kc += 64) {
    gl2lds16(Ag0 + kc,               As0);
    gl2lds16(Ag0 + 64 * K + kc,      As0 + 2048);
    gl2lds16(Ag0 + kc + 32,          As0 + 4096);
    gl2lds16(Ag0 + 64 * K + kc + 32, As0 + 6144);
    gl2lds16(Bg0 + kc,               Bs0);
    gl2lds16(Bg0 + 64 * K + kc,      Bs0 + 2048);
    gl2lds16(Bg0 + kc + 32,          Bs0 + 4096);
    gl2lds16(Bg0 + 64 * K + kc + 32, Bs0 + 6144);
    __syncthreads();

    bf16x8 af[4], bfr[4];
    // ---- kk0 (K 0..31 of this step) ----
#pragma unroll
    for (int mt = 0; mt < 4; mt++)
      af[mt] = *(const bf16x8*)&As[a_rd + mt * 512];
#pragma unroll
    for (int nt = 0; nt < 4; nt++)
      bfr[nt] = *(const bf16x8*)&Bs[b_rd + nt * 512];
#pragma unroll
    for (int mt = 0; mt < 4; mt++)
#pragma unroll
      for (int nt = 0; nt < 4; nt++)
        acc[mt][nt] = __builtin_amdgcn_mfma_f32_16x16x32_bf16(af[mt], bfr[nt], acc[mt][nt], 0, 0, 0);

    // ---- kk1 (K 32..63 of this step) ----
    bf16x8 af1[4], bfr1[4];
#pragma unroll
    for (int mt = 0; mt < 4; mt++)
      af1[mt] = *(const bf16x8*)&As[4096 + a_rd + mt * 512];
#pragma unroll
    for (int nt = 0; nt < 4; nt++)
      bfr1[nt] = *(const bf16x8*)&Bs[4096 + b_rd + nt * 512];
#pragma unroll
    for (int mt = 0; mt < 4; mt++)
#pragma unroll
      for (int nt = 0; nt < 4; nt++)
        acc[mt][nt] = __builtin_amdgcn_mfma_f32_16x16x32_bf16(af1[mt], bfr1[nt], acc[mt][nt], 0, 0, 0);
    __syncthreads();
  }

#pragma unroll
  for (int nt = 0; nt < 4; nt++) {
    const int n = bn0 + wn * 64 + nt * 16 + l15;
    float bv = 0.f;
    if (MODE == 1) bv = bias[n];
#pragma unroll
    for (int mt = 0; mt < 4; mt++) {
      const int mbase = bm0 + wm * 64 + mt * 16 + quad * 4;
#pragma unroll
      for (int r = 0; r < 4; r++) {
        const long m = mbase + r;
        if (MODE == 0) cbf[m * N + n] = (__bf16)acc[mt][nt][r];
        else           cf32[m * N + n] = acc[mt][nt][r] + bv;
      }
    }
  }
}

// ---------------- V transpose: qkv natural layout -> vt[bh][d][s] --------
__global__ __launch_bounds__(256) void transv(const __bf16* __restrict__ qkv,
                                              __bf16* __restrict__ vt) {
  __shared__ __align__(16) __bf16 T[64 * 64];
  const int tid = threadIdx.x, wave = tid >> 6;
  const int bh = blockIdx.x >> 5, st = blockIdx.x & 31;
  const int b = bh >> 4, h = bh & 15;
  const long gbase = (long)(b * Sq + st * 64 + (tid >> 3)) * N1q + h * 192 + 128 + (tid & 7) * 8;
  gl2lds16(qkv + gbase,                  T + wave * 512);
  gl2lds16(qkv + gbase + (long)32 * N1q, T + 2048 + wave * 512);
  __syncthreads();
  const int d = tid >> 2, s4 = (tid & 3) * 16;
  bf16x8 o0, o1;
#pragma unroll
  for (int j = 0; j < 8; j++) o0[j] = T[(s4 + j) * 64 + d];
#pragma unroll
  for (int j = 0; j < 8; j++) o1[j] = T[(s4 + 8 + j) * 64 + d];
  __bf16* dst = vt + (long)(bh * 64 + d) * Sq + st * 64 + s4;
  *(bf16x8*)dst = o0;
  *(bf16x8*)(dst + 8) = o1;
}

// ---------------- flash attention fwd (causal), transposed-scores --------
// Grid 1024, blockIdx = j*256 + k*64 + bh; qt = 4*j + ((k+j)&3) (Latin
// square: per-CU-slot work uniform). Fixed-max base-2 softmax (scale folded
// into w_qkv cvt). Per-nf fusion keeps one f32x16 of scores live.
// P cross-half exchange via v_permlane32_swap_b32 (VALU) — replaces the
// ds_bpermute __shfl_xor pair that generated 8 LDS-conflict cycles each
// (4.46M SQ_LDS_BANK_CONFLICT/dispatch in r2) plus 8 cndmask selects.
// launch_bounds(256,2): do NOT tighten (r4: (256,4) forced 64 VGPR+spills).
__global__ __launch_bounds__(256, 2) void attn_fwd(const __bf16* __restrict__ qkv,
                                                   const __bf16* __restrict__ vt,
                                                   __bf16* __restrict__ aout) {
  __shared__ __align__(16) __bf16 Ks[128 * 64];   // [kcol][d], 16B chunks XOR-swizzled
  __shared__ __align__(16) __bf16 Vs[64 * 128];   // [d][kcol], XOR-swizzled

  const int tid = threadIdx.x;
  const int w = tid >> 6, lane = tid & 63;
  const int c = lane & 31, h = lane >> 5;
  const int bi = blockIdx.x;
  const int bh = bi & 63, kk = (bi >> 6) & 3, jr = bi >> 8;
  const int qt = 4 * jr + ((kk + jr) & 3);
  const int b = bh >> 4, head = bh & 15;

  const int krr = lane >> 3, kj = lane & 7;
  const int vrr = lane >> 4, vj = lane & 15;

  const int q_g = qt * 128 + w * 32 + c;

  bf16x8 qf[4];
  const __bf16* qp = qkv + (long)(b * Sq + q_g) * N1q + head * 192 + h * 8;
#pragma unroll
  for (int kc2 = 0; kc2 < 4; kc2++) qf[kc2] = *(const bf16x8*)(qp + kc2 * 16);

  f32x16 oT[2] = {};
  float l_i = 0.f;
  constexpr float MB = 16.0f;   // fixed softmax max (base-2 domain)

  const int nk = qt + 1;
  for (int kt = 0; kt < nk; kt++) {
#pragma unroll
    for (int i = 0; i < 4; i++) {
      const int row = w * 32 + i * 8 + krr;
      gl2lds16(qkv + (long)(b * Sq + kt * 128 + row) * N1q + head * 192 + 64
                   + (kj ^ (krr & 7)) * 8,
               Ks + (w * 32 + i * 8) * 64);
    }
#pragma unroll
    for (int i = 0; i < 4; i++) {
      const int dr = w * 16 + i * 4 + vrr;
      gl2lds16(vt + (long)(bh * 64 + dr) * Sq + kt * 128 + (vj ^ (dr & 7)) * 8,
               Vs + (w * 16 + i * 4) * 128);
    }
    __syncthreads();

    const bool diag = (kt == qt);
    float s_acc = 0.f;

#pragma unroll
    for (int nf = 0; nf < 4; nf++) {
      f32x16 z = {};
#pragma unroll
      for (int kc2 = 0; kc2 < 4; kc2++) {
        bf16x8 kf = *(const bf16x8*)&Ks[(nf * 32 + c) * 64 + (((kc2 * 2 + h) ^ (c & 7)) * 8)];
        z = __builtin_amdgcn_mfma_f32_32x32x16_bf16(kf, qf[kc2], z, 0, 0, 0);
      }
      if (diag) {
#pragma unroll
        for (int r = 0; r < 16; r++) {
          const int kcol = kt * 128 + nf * 32 + (r & 3) + 8 * (r >> 2) + 4 * h;
          if (kcol > q_g) z[r] = -1e30f;
        }
      }
#pragma unroll
      for (int r = 0; r < 16; r++) {
        float p = fexp2(z[r] - MB);
        z[r] = p; s_acc += p;
      }
#pragma unroll
      for (int sub = 0; sub < 2; sub++) {
        const int kc = nf * 2 + sub, base = 8 * sub;
        unsigned pa0 = pack2(z[base + 0], z[base + 1]);
        unsigned pa1 = pack2(z[base + 2], z[base + 3]);
        unsigned pb0 = pack2(z[base + 4], z[base + 5]);
        unsigned pb1 = pack2(z[base + 6], z[base + 7]);
        // pa' = [pa.lo, pb.lo], pb' = [pa.hi, pb.hi] — identical data
        // movement to the old shfl_xor/select block, on the VALU pipe.
        perm32swap(pa0, pb0);
        perm32swap(pa1, pb1);
        union { bf16x8 v; unsigned u[4]; } pf;
        pf.u[0] = pa0;
        pf.u[1] = pa1;
        pf.u[2] = pb0;
        pf.u[3] = pb1;
#pragma unroll
        for (int nf2 = 0; nf2 < 2; nf2++) {
          bf16x8 vf = *(const bf16x8*)&Vs[(nf2 * 32 + c) * 128 + (((kc * 2 + h) ^ (c & 7)) * 8)];
          oT[nf2] = __builtin_amdgcn_mfma_f32_32x32x16_bf16(vf, pf.v, oT[nf2], 0, 0, 0);
        }
      }
    }
    l_i += s_acc;
    __syncthreads();
  }

  // ---- epilogue ----
  const float l = l_i + __shfl_xor(l_i, 32);
  const float inv = 1.0f / l;
  const long obase = (long)(b * Sq + q_g) * Eq + head * 64;
#pragma unroll
  for (int nf2 = 0; nf2 < 2; nf2++)
#pragma unroll
    for (int g = 0; g < 4; g++) {
      bf16x4 o;
#pragma unroll
      for (int t = 0; t < 4; t++) o[t] = (__bf16)(oT[nf2][g * 4 + t] * inv);
      *(bf16x4*)(aout + obase + nf2 * 32 + 8 * g + 4 * h) = o;
    }
}

// ---------------- launch ----------------
extern "C" void kernel_launch(void* const* d_in, const int* in_sizes, int n_in,
                              void* d_out, int out_size, void* d_ws, size_t ws_size,
                              hipStream_t stream) {
  const float* x      = (const float*)d_in[0];
  const float* w_qkv  = (const float*)d_in[1];
  const float* w_proj = (const float*)d_in[2];
  const float* b_proj = (const float*)d_in[3];
  float* out = (float*)d_out;

  char* w = (char*)d_ws;
  __bf16* xb     = (__bf16*)w; w += (size_t)Mq * Kq * 2;
  __bf16* wqkvb  = (__bf16*)w; w += (size_t)N1q * Kq * 2;
  __bf16* wprojb = (__bf16*)w; w += (size_t)Eq * Kq * 2;
  __bf16* qkvb   = (__bf16*)w; w += (size_t)Mq * N1q * 2;
  __bf16* vtb    = (__bf16*)w; w += (size_t)Bq * Hq * HDq * Sq * 2;
  __bf16* attnb  = (__bf16*)w;

  cvt_all<<<(NX4 + NW4 + NP4) / 256, 256, 0, stream>>>(x, w_qkv, w_proj, xb, wqkvb, wprojb);

  gemm_bt<0><<<dim3(Mq / 128, N1q / 128), 256, 0, stream>>>(xb, wqkvb, N1q, Kq, qkvb, nullptr, nullptr);

  transv<<<Bq * Hq * (Sq / 64), 256, 0, stream>>>(qkvb, vtb);

  attn_fwd<<<16 * 64, 256, 0, stream>>>(qkvb, vtb, attnb);

  gemm_bt<1><<<dim3(Mq / 128, Eq / 128), 256, 0, stream>>>(attnb, wprojb, Eq, Kq, nullptr, b_proj, out);
}